// Round 6
// baseline (255.505 us; speedup 1.0000x reference)
//
#include <hip/hip_runtime.h>

// Problem constants
#define BN   4
#define NN   128
#define INF  256
#define EF   128
#define OUTF 128
#define EPSF 1e-5f
#define NEGF -998244352.0f   // bf16(1e9); matches the bf16-rounded np reference

typedef __attribute__((ext_vector_type(8))) short short8;
typedef __attribute__((ext_vector_type(4))) float f32x4;

#define MFMA16(a, b, c) __builtin_amdgcn_mfma_f32_16x16x32_bf16(a, b, c, 0, 0, 0)

// fp32 -> bf16 round-to-nearest-even
__device__ __forceinline__ unsigned short f2bf(float f) {
    unsigned u = __float_as_uint(f);
    u += 0x7fffu + ((u >> 16) & 1u);
    return (unsigned short)(u >> 16);
}
__device__ __forceinline__ unsigned pack2(float a, float b) {
    return (unsigned)f2bf(a) | ((unsigned)f2bf(b) << 16);
}

// ---- workspace layout (float offsets) ----
constexpr size_t TRI1 = 0;            // B*N*8   tri_1 (masked)
constexpr size_t TRI2 = 4096;
constexpr size_t TRI3 = 8192;
constexpr size_t MSG1 = 12288;        // B*N*128 msg_1 (masked)
constexpr size_t MSG2 = 77824;
constexpr size_t ZWU1 = 143360;
constexpr size_t TRIG = 208896;       // B*8
constexpr size_t MSGG = 209920;       // B*128
constexpr size_t E1T  = 210944;       // B*N*N*8  [b][j][i][c]
constexpr size_t E2T  = 735232;       // B*N*N*8  [b][k][i][c]
constexpr size_t E3N  = 1259520;      // B*N*N*8  [b][j][k][c]
constexpr size_t PREPF = 1783808;     // bf16 prepped weights (ushort region)

// prep region offsets (ushort units)
constexpr int W1T_OFF  = 0;       // [n][k] 128x128
constexpr int W2T_OFF  = 16384;
constexpr int WMET_OFF = 32768;
constexpr int WET_OFF  = 49152;   // [n][k] 32x128 packed We1|We2|We3|0

// ---- output layout (float offsets): ret, msgs, tri_msgs ----
constexpr size_t O_RET = 0;
constexpr size_t O_MSG = 65536;
constexpr size_t O_TRI = 131072;

// bool arrays arrive as 1-byte bools or int32. mask[0][1..3] are always true
// (lengths >= 64); for int32 bools those bytes are high bytes of mask[0][0]=0.
__device__ __forceinline__ int detect_int(const void* mask) {
    const unsigned char* m = (const unsigned char*)mask;
    return (m[1] | m[2] | m[3]) == 0 ? 1 : 0;
}
__device__ __forceinline__ bool rdbool(const void* p, size_t idx, int isInt) {
    if (isInt) return ((const int*)p)[idx] != 0;
    return ((const unsigned char*)p)[idx] != 0;
}

// ============================================================
// K1: z projections (0..511) + graph proj (512..515) + weight prep (516..723)
// ============================================================
__global__ __launch_bounds__(256) void k_pre(
    const float* __restrict__ z, const void* __restrict__ mask,
    const float* __restrict__ Wt1, const float* __restrict__ Wt2, const float* __restrict__ Wt3,
    const float* __restrict__ Wm1, const float* __restrict__ Wm2, const float* __restrict__ WU1,
    const float* __restrict__ g, const float* __restrict__ Wg, const float* __restrict__ Wmg,
    const float* __restrict__ W1, const float* __restrict__ W2, const float* __restrict__ Wme,
    const float* __restrict__ We1, const float* __restrict__ We2, const float* __restrict__ We3,
    float* __restrict__ ws, unsigned short* __restrict__ prep)
{
    int bx = blockIdx.x, tid = threadIdx.x;
    if (bx >= 516) {               // ---- weight prep ----
        int idx = (bx - 516) * 256 + tid;
        if (idx < 49152) {
            const float* W = (idx < 16384) ? W1 : (idx < 32768 ? W2 : Wme);
            int i2 = idx & 16383;
            int n = i2 >> 7, k = i2 & 127;
            prep[idx] = f2bf(W[k * 128 + n]);
        } else {
            int i2 = idx - 49152;
            int n = i2 >> 7, k = i2 & 127;
            float v = 0.f;
            if (n < 8)       v = We1[k * 8 + n];
            else if (n < 16) v = We2[k * 8 + (n - 8)];
            else if (n < 24) v = We3[k * 8 + (n - 16)];
            prep[idx] = f2bf(v);
        }
        return;
    }
    if (bx >= 512) {               // ---- graph_fts projections ----
        int b = bx - 512;
        __shared__ float gr[128];
        if (tid < 128) gr[tid] = g[b * 128 + tid];
        __syncthreads();
        if (tid < 8) {
            float a = 0.f;
            for (int k = 0; k < 128; k++) a += gr[k] * Wg[k * 8 + tid];
            ws[TRIG + b * 8 + tid] = a;
        } else if (tid >= 128) {
            int c = tid - 128;
            float a = 0.f;
            for (int k = 0; k < 128; k++) a += gr[k] * Wmg[k * 128 + c];
            ws[MSGG + b * 128 + c] = a;
        }
        return;
    }
    // ---- z-row projections ----
    int bn = bx;
    int isInt = detect_int(mask);
    __shared__ float zr[INF];
    zr[tid] = z[(size_t)bn * INF + tid];
    __syncthreads();
    float mk = rdbool(mask, bn, isInt) ? 1.f : 0.f;
    for (int idx = tid; idx < 408; idx += 256) {
        const float* W; int c; size_t dst; int width; bool msk;
        if (idx < 8)        { W = Wt1; c = idx;       dst = TRI1 + (size_t)bn * 8;   width = 8;   msk = true;  }
        else if (idx < 16)  { W = Wt2; c = idx - 8;   dst = TRI2 + (size_t)bn * 8;   width = 8;   msk = true;  }
        else if (idx < 24)  { W = Wt3; c = idx - 16;  dst = TRI3 + (size_t)bn * 8;   width = 8;   msk = true;  }
        else if (idx < 152) { W = Wm1; c = idx - 24;  dst = MSG1 + (size_t)bn * 128; width = 128; msk = true;  }
        else if (idx < 280) { W = Wm2; c = idx - 152; dst = MSG2 + (size_t)bn * 128; width = 128; msk = true;  }
        else                { W = WU1; c = idx - 280; dst = ZWU1 + (size_t)bn * 128; width = 128; msk = false; }
        float acc = 0.f;
        #pragma unroll 8
        for (int k = 0; k < INF; k++) acc += zr[k] * W[k * width + c];
        ws[dst + c] = msk ? acc * mk : acc;
    }
}

// ============================================================
// K2: interleaved pair-MLP blocks (even) + tri-e projection blocks (odd).
// grid 1024, block 256.  All LDS traffic is wave-local (wave w owns Ab rows
// 32w..32w+31), so no __syncthreads except the final cross-wave max.
// B-fragments are read directly from L2-hot prep (no LDS weight staging):
// LDS = 36.9 KB -> 3-4 blocks/CU.
// ============================================================
__global__ __launch_bounds__(256, 3) void k_main(
    const float* __restrict__ e, const void* __restrict__ mask, const void* __restrict__ adj,
    const float* __restrict__ ln1s, const float* __restrict__ ln1o,
    const float* __restrict__ ln2s, const float* __restrict__ ln2o,
    const unsigned short* __restrict__ prep,
    float* __restrict__ ws, float* __restrict__ out)
{
    int unit = blockIdx.x >> 1;
    int tid = threadIdx.x;
    __shared__ __align__(16) unsigned short Ab[128 * 136];
    __shared__ float pw[512];

    int lane = tid & 63, w = tid >> 6, q = lane >> 4, n = lane & 15;

    if (blockIdx.x & 1) {
        // ================= tri-e projection: block = one (b,i) =================
        int bi = unit;
        int b = bi >> 7, i = bi & 127;
        {
            int r = tid >> 1, h = tid & 1;
            const float4* ep = (const float4*)(e + (size_t)bi * 16384 + (size_t)r * 128 + h * 64);
            unsigned* dst = (unsigned*)&Ab[r * 136 + h * 64];
            #pragma unroll
            for (int q2 = 0; q2 < 16; q2++) {
                float4 v = ep[q2];
                dst[q2 * 2]     = pack2(v.x, v.y);
                dst[q2 * 2 + 1] = pack2(v.z, v.w);
            }
        }
        __builtin_amdgcn_wave_barrier();   // wave-local rows; no block barrier needed

        f32x4 ac2[2][2];
        #pragma unroll
        for (int rt = 0; rt < 2; rt++)
            #pragma unroll
            for (int t = 0; t < 2; t++) ac2[rt][t] = 0.f;
        #pragma unroll
        for (int ks = 0; ks < 4; ks++) {
            int k0 = ks * 32 + q * 8;
            short8 a0 = *(const short8*)&Ab[(32 * w + n) * 136 + k0];
            short8 a1 = *(const short8*)&Ab[(32 * w + 16 + n) * 136 + k0];
            #pragma unroll
            for (int t = 0; t < 2; t++) {
                short8 bt = *(const short8*)&prep[WET_OFF + (16 * t + n) * 128 + k0];
                ac2[0][t] = MFMA16(a0, bt, ac2[0][t]);
                ac2[1][t] = MFMA16(a1, bt, ac2[1][t]);
            }
        }
        #pragma unroll
        for (int rt = 0; rt < 2; rt++)
            #pragma unroll
            for (int reg = 0; reg < 4; reg++) {
                int row = 32 * w + 16 * rt + 4 * q + reg;
                float v0 = ac2[rt][0][reg];
                if (n < 8) ws[E1T + ((size_t)(b * 128 + row) * 128 + i) * 8 + n] = v0;
                else       ws[E2T + ((size_t)(b * 128 + row) * 128 + i) * 8 + (n - 8)] = v0;
                if (n < 8) ws[E3N + ((size_t)bi * 128 + row) * 8 + n] = ac2[rt][1][reg];
            }
        return;
    }

    // ================= pair MLP: block = one (b,j) =================
    int bj = unit;
    int b = bj >> 7, j = bj & 127;
    int isInt = detect_int(mask);

    // stage e-slice e[b, :, j, :] -> bf16 Ab (wave-local rows)
    {
        int r = tid >> 1, h = tid & 1;
        const float4* ep = (const float4*)(e + (((size_t)b * 128 + r) * 128 + j) * 128 + h * 64);
        unsigned* dst = (unsigned*)&Ab[r * 136 + h * 64];
        #pragma unroll
        for (int q2 = 0; q2 < 16; q2++) {
            float4 v = ep[q2];
            dst[q2 * 2]     = pack2(v.x, v.y);
            dst[q2 * 2 + 1] = pack2(v.z, v.w);
        }
    }
    __builtin_amdgcn_wave_barrier();

    f32x4 acc[2][8];
    #pragma unroll
    for (int rt = 0; rt < 2; rt++)
        #pragma unroll
        for (int t = 0; t < 8; t++) acc[rt][t] = 0.f;

    // ---- GEMM0: msge_pre = E_slice @ Wme (B direct from global) ----
    #pragma unroll
    for (int ks = 0; ks < 4; ks++) {
        int k0 = ks * 32 + q * 8;
        short8 a0 = *(const short8*)&Ab[(32 * w + n) * 136 + k0];
        short8 a1 = *(const short8*)&Ab[(32 * w + 16 + n) * 136 + k0];
        #pragma unroll
        for (int t = 0; t < 8; t++) {
            short8 bt = *(const short8*)&prep[WMET_OFF + (16 * t + n) * 128 + k0];
            acc[0][t] = MFMA16(a0, bt, acc[0][t]);
            acc[1][t] = MFMA16(a1, bt, acc[1][t]);
        }
    }

    // ---- T = (adj? msge:0) + msg2[row] + msg1[j] + msgg;  LN1 + relu -> Ab ----
    float msum[8];
    #pragma unroll
    for (int t = 0; t < 8; t++)
        msum[t] = ws[MSG1 + (size_t)bj * 128 + 16 * t + n] + ws[MSGG + (size_t)b * 128 + 16 * t + n];
    float adjm[2][4];
    float rs[2][4], rss[2][4];
    #pragma unroll
    for (int rt = 0; rt < 2; rt++)
        #pragma unroll
        for (int reg = 0; reg < 4; reg++) {
            int row = 32 * w + 16 * rt + 4 * q + reg;
            bool av = rdbool(adj, ((size_t)b * 128 + row) * 128 + j, isInt);
            adjm[rt][reg] = av ? 1.f : 0.f;
            float s = 0.f, ssq = 0.f;
            #pragma unroll
            for (int t = 0; t < 8; t++) {
                float v = acc[rt][t][reg] * adjm[rt][reg]
                        + ws[MSG2 + ((size_t)b * 128 + row) * 128 + 16 * t + n] + msum[t];
                acc[rt][t][reg] = v;
                s += v; ssq += v * v;
            }
            rs[rt][reg] = s; rss[rt][reg] = ssq;
        }
    #pragma unroll
    for (int d = 1; d < 16; d <<= 1) {
        #pragma unroll
        for (int rt = 0; rt < 2; rt++)
            #pragma unroll
            for (int reg = 0; reg < 4; reg++) {
                rs[rt][reg]  += __shfl_xor(rs[rt][reg], d, 64);
                rss[rt][reg] += __shfl_xor(rss[rt][reg], d, 64);
            }
    }
    {
        float s1v[8], o1v[8];
        #pragma unroll
        for (int t = 0; t < 8; t++) { s1v[t] = ln1s[16 * t + n]; o1v[t] = ln1o[16 * t + n]; }
        #pragma unroll
        for (int rt = 0; rt < 2; rt++)
            #pragma unroll
            for (int reg = 0; reg < 4; reg++) {
                float mu = rs[rt][reg] * (1.f / 128);
                float inv = rsqrtf(rss[rt][reg] * (1.f / 128) - mu * mu + EPSF);
                int row = 32 * w + 16 * rt + 4 * q + reg;
                #pragma unroll
                for (int t = 0; t < 8; t++) {
                    float v = fmaxf(s1v[t] * inv * (acc[rt][t][reg] - mu) + o1v[t], 0.f);
                    Ab[row * 136 + 16 * t + n] = f2bf(v);
                }
            }
    }
    __builtin_amdgcn_wave_barrier();   // LN1 writes are wave-local

    // ---- GEMM1 ----
    #pragma unroll
    for (int rt = 0; rt < 2; rt++)
        #pragma unroll
        for (int t = 0; t < 8; t++) acc[rt][t] = 0.f;
    #pragma unroll
    for (int ks = 0; ks < 4; ks++) {
        int k0 = ks * 32 + q * 8;
        short8 a0 = *(const short8*)&Ab[(32 * w + n) * 136 + k0];
        short8 a1 = *(const short8*)&Ab[(32 * w + 16 + n) * 136 + k0];
        #pragma unroll
        for (int t = 0; t < 8; t++) {
            short8 bt = *(const short8*)&prep[W1T_OFF + (16 * t + n) * 128 + k0];
            acc[0][t] = MFMA16(a0, bt, acc[0][t]);
            acc[1][t] = MFMA16(a1, bt, acc[1][t]);
        }
    }
    // ---- LN2 + relu -> Ab ----
    #pragma unroll
    for (int rt = 0; rt < 2; rt++)
        #pragma unroll
        for (int reg = 0; reg < 4; reg++) {
            float s = 0.f, ssq = 0.f;
            #pragma unroll
            for (int t = 0; t < 8; t++) { float v = acc[rt][t][reg]; s += v; ssq += v * v; }
            rs[rt][reg] = s; rss[rt][reg] = ssq;
        }
    #pragma unroll
    for (int d = 1; d < 16; d <<= 1) {
        #pragma unroll
        for (int rt = 0; rt < 2; rt++)
            #pragma unroll
            for (int reg = 0; reg < 4; reg++) {
                rs[rt][reg]  += __shfl_xor(rs[rt][reg], d, 64);
                rss[rt][reg] += __shfl_xor(rss[rt][reg], d, 64);
            }
    }
    {
        float s2v[8], o2v[8];
        #pragma unroll
        for (int t = 0; t < 8; t++) { s2v[t] = ln2s[16 * t + n]; o2v[t] = ln2o[16 * t + n]; }
        #pragma unroll
        for (int rt = 0; rt < 2; rt++)
            #pragma unroll
            for (int reg = 0; reg < 4; reg++) {
                float mu = rs[rt][reg] * (1.f / 128);
                float inv = rsqrtf(rss[rt][reg] * (1.f / 128) - mu * mu + EPSF);
                int row = 32 * w + 16 * rt + 4 * q + reg;
                #pragma unroll
                for (int t = 0; t < 8; t++) {
                    float v = fmaxf(s2v[t] * inv * (acc[rt][t][reg] - mu) + o2v[t], 0.f);
                    Ab[row * 136 + 16 * t + n] = f2bf(v);
                }
            }
    }
    __builtin_amdgcn_wave_barrier();

    // ---- GEMM2 ----
    #pragma unroll
    for (int rt = 0; rt < 2; rt++)
        #pragma unroll
        for (int t = 0; t < 8; t++) acc[rt][t] = 0.f;
    #pragma unroll
    for (int ks = 0; ks < 4; ks++) {
        int k0 = ks * 32 + q * 8;
        short8 a0 = *(const short8*)&Ab[(32 * w + n) * 136 + k0];
        short8 a1 = *(const short8*)&Ab[(32 * w + 16 + n) * 136 + k0];
        #pragma unroll
        for (int t = 0; t < 8; t++) {
            short8 bt = *(const short8*)&prep[W2T_OFF + (16 * t + n) * 128 + k0];
            acc[0][t] = MFMA16(a0, bt, acc[0][t]);
            acc[1][t] = MFMA16(a1, bt, acc[1][t]);
        }
    }
    // ---- adj mask + max over rows i ----
    float colmax[8];
    #pragma unroll
    for (int t = 0; t < 8; t++) colmax[t] = NEGF;
    #pragma unroll
    for (int rt = 0; rt < 2; rt++)
        #pragma unroll
        for (int reg = 0; reg < 4; reg++) {
            if (adjm[rt][reg] > 0.f) {
                #pragma unroll
                for (int t = 0; t < 8; t++) colmax[t] = fmaxf(colmax[t], acc[rt][t][reg]);
            }
        }
    #pragma unroll
    for (int t = 0; t < 8; t++) {
        colmax[t] = fmaxf(colmax[t], __shfl_xor(colmax[t], 16, 64));
        colmax[t] = fmaxf(colmax[t], __shfl_xor(colmax[t], 32, 64));
    }
    if (lane < 16) {
        #pragma unroll
        for (int t = 0; t < 8; t++) pw[w * 128 + 16 * t + lane] = colmax[t];
    }
    __syncthreads();   // the one true cross-wave rendezvous
    if (tid < 128) {
        float mx = fmaxf(fmaxf(pw[tid], pw[128 + tid]), fmaxf(pw[256 + tid], pw[384 + tid]));
        out[O_MSG + (size_t)bj * 128 + tid] = mx;
    }
}

// ============================================================
// K3: triplet pooling (blocks 0..255) + final LN (blocks 256..319).
// block 1024.
// ============================================================
constexpr int PSTR = 1032;   // 1032 % 32 = 8
constexpr int QSTR = 1036;   // 1036 % 32 = 12 -> 2-way (free)

__global__ __launch_bounds__(1024) void k_post(
    const float* __restrict__ ws, const void* __restrict__ mask,
    const float* __restrict__ WU3, const float* __restrict__ WU2,
    const float* __restrict__ lnfs, const float* __restrict__ lnfo,
    float* __restrict__ out)
{
    int tid = threadIdx.x;
    __shared__ __align__(16) float smem[16 * PSTR + 16 * QSTR];
    __shared__ unsigned char mloc[128];

    if (blockIdx.x >= 256) {
        // ---------------- final: ret = LN(z@WU1 + msgs@WU2) ----------------
        int blk = blockIdx.x - 256;        // 0..63
        int r8 = tid >> 7, col = tid & 127;
        int bn = blk * 8 + r8;
        float* mrows = smem;               // [8][128]
        float* red   = smem + 1024;        // [32]
        mrows[tid] = out[O_MSG + (size_t)bn * 128 + col];
        __syncthreads();
        float y = ws[ZWU1 + (size_t)bn * 128 + col];
        #pragma unroll 8
        for (int k = 0; k < 128; k++) y += mrows[r8 * 128 + k] * WU2[k * 128 + col];
        float s = y, ss = y * y;
        for (int d = 1; d < 64; d <<= 1) { s += __shfl_xor(s, d, 64); ss += __shfl_xor(ss, d, 64); }
        int wv = tid >> 6;
        if ((tid & 63) == 0) { red[2 * wv] = s; red[2 * wv + 1] = ss; }
        __syncthreads();
        float S = red[4 * r8] + red[4 * r8 + 2], SS = red[4 * r8 + 1] + red[4 * r8 + 3];
        float m_ = S * (1.f / 128), v_ = SS * (1.f / 128) - m_ * m_;
        float r = rsqrtf(v_ + EPSF);
        out[O_RET + (size_t)bn * 128 + col] = lnfs[col] * r * (y - m_) + lnfo[col];
        return;
    }

    // ---------------- triplet max-plus pooling ----------------
    int bx = blockIdx.x;
    int j0 = (bx & 7) * 16, k0 = ((bx >> 3) & 7) * 16, b = bx >> 6;
    int isInt = detect_int(mask);
    float* Pl = smem;               // [16][PSTR]
    float* Ql = smem + 16 * PSTR;   // [16][QSTR]
    float* red    = smem;                  // phase-2 aliases (P region dead)
    float* pooled = smem + 8192;
    float* WU3l   = smem + 8192 + 2048;

    if (tid < 128) mloc[tid] = rdbool(mask, b * 128 + tid, isInt) ? 1 : 0;

    {
        int r   = tid >> 6;
        int off = (tid & 63) * 16;
        const float4* e1 = (const float4*)(ws + E1T + (size_t)(b * 128 + j0 + r) * 1024 + off);
        const float4* t1 = (const float4*)(ws + TRI1 + (size_t)b * 1024 + off);
        const float4* e2 = (const float4*)(ws + E2T + (size_t)(b * 128 + k0 + r) * 1024 + off);
        float* pd = Pl + r * PSTR + off;
        float* qd = Ql + r * QSTR + off;
        #pragma unroll
        for (int t = 0; t < 4; t++) {
            float4 a = e1[t], bb = t1[t], qv = e2[t];
            pd[t * 4 + 0] = a.x + bb.x; pd[t * 4 + 1] = a.y + bb.y;
            pd[t * 4 + 2] = a.z + bb.z; pd[t * 4 + 3] = a.w + bb.w;
            qd[t * 4 + 0] = qv.x; qd[t * 4 + 1] = qv.y;
            qd[t * 4 + 2] = qv.z; qd[t * 4 + 3] = qv.w;
        }
    }
    __syncthreads();

    int ic = tid >> 8;
    int tj = (tid >> 4) & 15, tk = tid & 15;
    float accM[8], accU[8];
    #pragma unroll
    for (int c = 0; c < 8; c++) { accM[c] = NEGF; accU[c] = NEGF; }
    {
        const float* pp = Pl + tj * PSTR;
        const float* qq = Ql + tk * QSTR;
        int i1 = ic * 32 + 32;
        for (int ii = ic * 32; ii < i1; ii++) {
            bool m_i = mloc[ii] != 0;
            float4 p0 = *(const float4*)(pp + ii * 8);
            float4 p1 = *(const float4*)(pp + ii * 8 + 4);
            float4 q0 = *(const float4*)(qq + ii * 8);
            float4 q1 = *(const float4*)(qq + ii * 8 + 4);
            float v[8] = { p0.x + q0.x, p0.y + q0.y, p0.z + q0.z, p0.w + q0.w,
                           p1.x + q1.x, p1.y + q1.y, p1.z + q1.z, p1.w + q1.w };
            if (m_i) {
                #pragma unroll
                for (int c = 0; c < 8; c++) accM[c] = fmaxf(accM[c], v[c]);
            } else {
                #pragma unroll
                for (int c = 0; c < 8; c++) accU[c] = fmaxf(accU[c], v[c]);
            }
        }
    }
    float sel[8];
    {
        bool all_i = (mloc[j0 + tj] | mloc[k0 + tk]) != 0;
        #pragma unroll
        for (int c = 0; c < 8; c++) sel[c] = all_i ? fmaxf(accM[c], accU[c]) : accM[c];
    }
    __syncthreads();
    #pragma unroll
    for (int c = 0; c < 8; c++) red[c * 1024 + tid] = sel[c];
    __syncthreads();

    if (tid < 256) {
        int rtj = tid >> 4, rtk = tid & 15;
        const float* t2 = ws + TRI2 + (size_t)(b * 128 + j0 + rtj) * 8;
        const float* t3 = ws + TRI3 + (size_t)(b * 128 + k0 + rtk) * 8;
        const float* e3 = ws + E3N + ((size_t)(b * 128 + j0 + rtj) * 128 + (k0 + rtk)) * 8;
        const float* tg = ws + TRIG + (size_t)b * 8;
        #pragma unroll
        for (int c = 0; c < 8; c++) {
            const float* rc = red + c * 1024 + tid;
            float v = fmaxf(fmaxf(rc[0], rc[256]), fmaxf(rc[512], rc[768]));
            pooled[tid * 8 + c] = v + t2[c] + t3[c] + e3[c] + tg[c];
        }
    } else if (tid < 512) {
        int m = tid - 256;
        *(float4*)(WU3l + m * 4) = *(const float4*)(WU3 + m * 4);
    }
    __syncthreads();

    int col4 = (tid & 31) * 4;
    #pragma unroll
    for (int pass = 0; pass < 8; pass++) {
        int p = pass * 32 + (tid >> 5);
        const float* pl = pooled + p * 8;
        float4 s = { 0.f, 0.f, 0.f, 0.f };
        #pragma unroll
        for (int c = 0; c < 8; c++) {
            float pv = pl[c];
            float4 wv = *(const float4*)(WU3l + c * 128 + col4);
            s.x += pv * wv.x; s.y += pv * wv.y; s.z += pv * wv.z; s.w += pv * wv.w;
        }
        s.x = fmaxf(s.x, 0.f); s.y = fmaxf(s.y, 0.f);
        s.z = fmaxf(s.z, 0.f); s.w = fmaxf(s.w, 0.f);
        int pj = p >> 4, pk = p & 15;
        *(float4*)(out + O_TRI + ((size_t)(b * 128 + j0 + pj) * 128 + (k0 + pk)) * 128 + col4) = s;
    }
}

// ============================================================
extern "C" void kernel_launch(void* const* d_in, const int* in_sizes, int n_in,
                              void* d_out, int out_size, void* d_ws, size_t ws_size,
                              hipStream_t stream)
{
    const float* z    = (const float*)d_in[0];
    const float* e    = (const float*)d_in[1];
    const float* gf   = (const float*)d_in[2];
    const void*  mask = d_in[3];
    const void*  adj  = d_in[4];
    const float* Wt1 = (const float*)d_in[5];
    const float* Wt2 = (const float*)d_in[6];
    const float* Wt3 = (const float*)d_in[7];
    const float* We1 = (const float*)d_in[8];
    const float* We2 = (const float*)d_in[9];
    const float* We3 = (const float*)d_in[10];
    const float* Wg  = (const float*)d_in[11];
    const float* Wm1 = (const float*)d_in[12];
    const float* Wm2 = (const float*)d_in[13];
    const float* Wme = (const float*)d_in[14];
    const float* Wmg = (const float*)d_in[15];
    const float* ln1s = (const float*)d_in[16];
    const float* ln1o = (const float*)d_in[17];
    const float* W1   = (const float*)d_in[18];
    const float* ln2s = (const float*)d_in[19];
    const float* ln2o = (const float*)d_in[20];
    const float* W2   = (const float*)d_in[21];
    const float* WU1  = (const float*)d_in[22];
    const float* WU2  = (const float*)d_in[23];
    const float* WU3  = (const float*)d_in[24];
    const float* lnfs = (const float*)d_in[25];
    const float* lnfo = (const float*)d_in[26];
    float* out = (float*)d_out;
    float* ws  = (float*)d_ws;
    unsigned short* prep = (unsigned short*)(ws + PREPF);

    hipLaunchKernelGGL(k_pre, dim3(724), dim3(256), 0, stream,
                       z, mask, Wt1, Wt2, Wt3, Wm1, Wm2, WU1, gf, Wg, Wmg,
                       W1, W2, Wme, We1, We2, We3, ws, prep);
    hipLaunchKernelGGL(k_main, dim3(1024), dim3(256), 0, stream,
                       e, mask, adj, ln1s, ln1o, ln2s, ln2o, prep, ws, out);
    hipLaunchKernelGGL(k_post, dim3(320), dim3(1024), 0, stream,
                       ws, mask, WU3, WU2, lnfs, lnfo, out);
}

// Round 7
// 230.407 us; speedup vs baseline: 1.1089x; 1.1089x over previous
//
#include <hip/hip_runtime.h>

// Problem constants
#define BN   4
#define NN   128
#define INF  256
#define EF   128
#define OUTF 128
#define EPSF 1e-5f
#define NEGF -998244352.0f   // bf16(1e9); matches the bf16-rounded np reference

typedef __attribute__((ext_vector_type(8))) short short8;
typedef __attribute__((ext_vector_type(4))) float f32x4;

#define MFMA16(a, b, c) __builtin_amdgcn_mfma_f32_16x16x32_bf16(a, b, c, 0, 0, 0)

// fp32 -> bf16 round-to-nearest-even
__device__ __forceinline__ unsigned short f2bf(float f) {
    unsigned u = __float_as_uint(f);
    u += 0x7fffu + ((u >> 16) & 1u);
    return (unsigned short)(u >> 16);
}
__device__ __forceinline__ unsigned pack2(float a, float b) {
    return (unsigned)f2bf(a) | ((unsigned)f2bf(b) << 16);
}

// ---- workspace layout (float offsets) ----
constexpr size_t TRI1 = 0;            // B*N*8   tri_1 (masked)
constexpr size_t TRI2 = 4096;
constexpr size_t TRI3 = 8192;
constexpr size_t MSG1 = 12288;        // B*N*128 msg_1 (masked)
constexpr size_t MSG2 = 77824;
constexpr size_t ZWU1 = 143360;
constexpr size_t TRIG = 208896;       // B*8
constexpr size_t MSGG = 209920;       // B*128
constexpr size_t E1T  = 210944;       // B*N*N*8  [b][j][i][c]
constexpr size_t E2T  = 735232;       // B*N*N*8  [b][k][i][c]
constexpr size_t E3N  = 1259520;      // B*N*N*8  [b][j][k][c]
constexpr size_t PREPF = 1783808;     // bf16 prepped weights (ushort region)

// prep region offsets (ushort units) — weights stored in MFMA-FRAGMENT ORDER:
// element ((ks*T + t)*64 + lane)*8 + jj  ==  W^T[16*t + (lane&15)][ks*32 + (lane>>4)*8 + jj]
// so a wave's B-fragment load is 64 consecutive 16B chunks (1KB coalesced).
constexpr int W1T_OFF  = 0;       // T=8, 16384 ushorts
constexpr int W2T_OFF  = 16384;
constexpr int WMET_OFF = 32768;
constexpr int WET_OFF  = 49152;   // T=2 (packed We1|We2 rows 0..15, We3|pad rows 16..31)

// ---- output layout (float offsets): ret, msgs, tri_msgs ----
constexpr size_t O_RET = 0;
constexpr size_t O_MSG = 65536;
constexpr size_t O_TRI = 131072;

// bool arrays arrive as 1-byte bools or int32. mask[0][1..3] are always true
// (lengths >= 64); for int32 bools those bytes are high bytes of mask[0][0]=0.
__device__ __forceinline__ int detect_int(const void* mask) {
    const unsigned char* m = (const unsigned char*)mask;
    return (m[1] | m[2] | m[3]) == 0 ? 1 : 0;
}
__device__ __forceinline__ bool rdbool(const void* p, size_t idx, int isInt) {
    if (isInt) return ((const int*)p)[idx] != 0;
    return ((const unsigned char*)p)[idx] != 0;
}

// ============================================================
// K1: z projections (0..511) + graph proj (512..515) + weight prep (516..723)
// ============================================================
__global__ __launch_bounds__(256) void k_pre(
    const float* __restrict__ z, const void* __restrict__ mask,
    const float* __restrict__ Wt1, const float* __restrict__ Wt2, const float* __restrict__ Wt3,
    const float* __restrict__ Wm1, const float* __restrict__ Wm2, const float* __restrict__ WU1,
    const float* __restrict__ g, const float* __restrict__ Wg, const float* __restrict__ Wmg,
    const float* __restrict__ W1, const float* __restrict__ W2, const float* __restrict__ Wme,
    const float* __restrict__ We1, const float* __restrict__ We2, const float* __restrict__ We3,
    float* __restrict__ ws, unsigned short* __restrict__ prep)
{
    int bx = blockIdx.x, tid = threadIdx.x;
    if (bx >= 516) {               // ---- weight prep (fragment-order layout) ----
        int idx = (bx - 516) * 256 + tid;
        if (idx < 49152) {
            const float* W = (idx < 16384) ? W1 : (idx < 32768 ? W2 : Wme);
            int local = idx & 16383;
            int f = local >> 3, jj = local & 7;
            int lane = f & 63, fg = f >> 6;
            int t = fg & 7, ks = fg >> 3;
            int n = lane & 15, q = lane >> 4;
            int row = 16 * t + n;
            int k = ks * 32 + q * 8 + jj;
            prep[idx] = f2bf(W[k * 128 + row]);
        } else if (idx < 53248) {
            int local = idx - 49152;
            int f = local >> 3, jj = local & 7;
            int lane = f & 63, fg = f >> 6;
            int t = fg & 1, ks = fg >> 1;
            int n = lane & 15, q = lane >> 4;
            int row = 16 * t + n;
            int k = ks * 32 + q * 8 + jj;
            float v = 0.f;
            if (row < 8)       v = We1[k * 8 + row];
            else if (row < 16) v = We2[k * 8 + (row - 8)];
            else if (row < 24) v = We3[k * 8 + (row - 16)];
            prep[idx] = f2bf(v);
        }
        return;
    }
    if (bx >= 512) {               // ---- graph_fts projections ----
        int b = bx - 512;
        __shared__ float gr[128];
        if (tid < 128) gr[tid] = g[b * 128 + tid];
        __syncthreads();
        if (tid < 8) {
            float a = 0.f;
            for (int k = 0; k < 128; k++) a += gr[k] * Wg[k * 8 + tid];
            ws[TRIG + b * 8 + tid] = a;
        } else if (tid >= 128) {
            int c = tid - 128;
            float a = 0.f;
            for (int k = 0; k < 128; k++) a += gr[k] * Wmg[k * 128 + c];
            ws[MSGG + b * 128 + c] = a;
        }
        return;
    }
    // ---- z-row projections ----
    int bn = bx;
    int isInt = detect_int(mask);
    __shared__ float zr[INF];
    zr[tid] = z[(size_t)bn * INF + tid];
    __syncthreads();
    float mk = rdbool(mask, bn, isInt) ? 1.f : 0.f;
    for (int idx = tid; idx < 408; idx += 256) {
        const float* W; int c; size_t dst; int width; bool msk;
        if (idx < 8)        { W = Wt1; c = idx;       dst = TRI1 + (size_t)bn * 8;   width = 8;   msk = true;  }
        else if (idx < 16)  { W = Wt2; c = idx - 8;   dst = TRI2 + (size_t)bn * 8;   width = 8;   msk = true;  }
        else if (idx < 24)  { W = Wt3; c = idx - 16;  dst = TRI3 + (size_t)bn * 8;   width = 8;   msk = true;  }
        else if (idx < 152) { W = Wm1; c = idx - 24;  dst = MSG1 + (size_t)bn * 128; width = 128; msk = true;  }
        else if (idx < 280) { W = Wm2; c = idx - 152; dst = MSG2 + (size_t)bn * 128; width = 128; msk = true;  }
        else                { W = WU1; c = idx - 280; dst = ZWU1 + (size_t)bn * 128; width = 128; msk = false; }
        float acc = 0.f;
        #pragma unroll 8
        for (int k = 0; k < INF; k++) acc += zr[k] * W[k * width + c];
        ws[dst + c] = msk ? acc * mk : acc;
    }
}

// ============================================================
// K2: interleaved pair-MLP blocks (even) + tri-e projection blocks (odd).
// grid 1024, block 256.  LDS rows are wave-local; B-fragments read from
// L2-hot fragment-ordered prep (coalesced 1KB/wave loads).
// ============================================================
__global__ __launch_bounds__(256, 4) void k_main(
    const float* __restrict__ e, const void* __restrict__ mask, const void* __restrict__ adj,
    const float* __restrict__ ln1s, const float* __restrict__ ln1o,
    const float* __restrict__ ln2s, const float* __restrict__ ln2o,
    const unsigned short* __restrict__ prep,
    float* __restrict__ ws, float* __restrict__ out)
{
    int unit = blockIdx.x >> 1;
    int tid = threadIdx.x;
    __shared__ __align__(16) unsigned short Ab[128 * 136];
    __shared__ float pw[512];

    int lane = tid & 63, w = tid >> 6, q = lane >> 4, n = lane & 15;

    if (blockIdx.x & 1) {
        // ================= tri-e projection: block = one (b,i) =================
        int bi = unit;
        int b = bi >> 7, i = bi & 127;
        // coalesced staging: 2 rows per instruction, 32 lanes per row
        {
            int half = lane >> 5, c4 = (lane & 31) * 4;
            #pragma unroll
            for (int it = 0; it < 16; it++) {
                int row = 32 * w + 2 * it + half;
                float4 v = *(const float4*)(e + (size_t)bi * 16384 + (size_t)row * 128 + c4);
                unsigned* dst = (unsigned*)&Ab[row * 136 + c4];
                dst[0] = pack2(v.x, v.y);
                dst[1] = pack2(v.z, v.w);
            }
        }
        __builtin_amdgcn_wave_barrier();   // wave-local rows; no block barrier needed

        f32x4 ac2[2][2];
        #pragma unroll
        for (int rt = 0; rt < 2; rt++)
            #pragma unroll
            for (int t = 0; t < 2; t++) ac2[rt][t] = 0.f;
        #pragma unroll
        for (int ks = 0; ks < 4; ks++) {
            int k0 = ks * 32 + q * 8;
            short8 a0 = *(const short8*)&Ab[(32 * w + n) * 136 + k0];
            short8 a1 = *(const short8*)&Ab[(32 * w + 16 + n) * 136 + k0];
            #pragma unroll
            for (int t = 0; t < 2; t++) {
                short8 bt = *(const short8*)&prep[WET_OFF + ((ks * 2 + t) * 64 + lane) * 8];
                ac2[0][t] = MFMA16(a0, bt, ac2[0][t]);
                ac2[1][t] = MFMA16(a1, bt, ac2[1][t]);
            }
        }
        #pragma unroll
        for (int rt = 0; rt < 2; rt++)
            #pragma unroll
            for (int reg = 0; reg < 4; reg++) {
                int row = 32 * w + 16 * rt + 4 * q + reg;
                float v0 = ac2[rt][0][reg];
                if (n < 8) ws[E1T + ((size_t)(b * 128 + row) * 128 + i) * 8 + n] = v0;
                else       ws[E2T + ((size_t)(b * 128 + row) * 128 + i) * 8 + (n - 8)] = v0;
                if (n < 8) ws[E3N + ((size_t)bi * 128 + row) * 8 + n] = ac2[rt][1][reg];
            }
        return;
    }

    // ================= pair MLP: block = one (b,j) =================
    int bj = unit;
    int b = bj >> 7, j = bj & 127;
    int isInt = detect_int(mask);

    // coalesced staging of e-slice e[b, :, j, :]: 2 rows/instr, 32 lanes/row
    {
        int half = lane >> 5, c4 = (lane & 31) * 4;
        #pragma unroll
        for (int it = 0; it < 16; it++) {
            int row = 32 * w + 2 * it + half;
            float4 v = *(const float4*)(e + (((size_t)b * 128 + row) * 128 + j) * 128 + c4);
            unsigned* dst = (unsigned*)&Ab[row * 136 + c4];
            dst[0] = pack2(v.x, v.y);
            dst[1] = pack2(v.z, v.w);
        }
    }
    __builtin_amdgcn_wave_barrier();

    f32x4 acc[2][8];
    #pragma unroll
    for (int rt = 0; rt < 2; rt++)
        #pragma unroll
        for (int t = 0; t < 8; t++) acc[rt][t] = 0.f;

    // ---- GEMM0: msge_pre = E_slice @ Wme (B coalesced from prep) ----
    #pragma unroll
    for (int ks = 0; ks < 4; ks++) {
        int k0 = ks * 32 + q * 8;
        short8 a0 = *(const short8*)&Ab[(32 * w + n) * 136 + k0];
        short8 a1 = *(const short8*)&Ab[(32 * w + 16 + n) * 136 + k0];
        #pragma unroll
        for (int t = 0; t < 8; t++) {
            short8 bt = *(const short8*)&prep[WMET_OFF + ((ks * 8 + t) * 64 + lane) * 8];
            acc[0][t] = MFMA16(a0, bt, acc[0][t]);
            acc[1][t] = MFMA16(a1, bt, acc[1][t]);
        }
    }

    // ---- T = (adj? msge:0) + msg2[row] + msg1[j] + msgg;  LN1 + relu -> Ab ----
    float msum[8];
    #pragma unroll
    for (int t = 0; t < 8; t++)
        msum[t] = ws[MSG1 + (size_t)bj * 128 + 16 * t + n] + ws[MSGG + (size_t)b * 128 + 16 * t + n];
    float adjm[2][4];
    float rs[2][4], rss[2][4];
    #pragma unroll
    for (int rt = 0; rt < 2; rt++)
        #pragma unroll
        for (int reg = 0; reg < 4; reg++) {
            int row = 32 * w + 16 * rt + 4 * q + reg;
            bool av = rdbool(adj, ((size_t)b * 128 + row) * 128 + j, isInt);
            adjm[rt][reg] = av ? 1.f : 0.f;
            float s = 0.f, ssq = 0.f;
            #pragma unroll
            for (int t = 0; t < 8; t++) {
                float v = acc[rt][t][reg] * adjm[rt][reg]
                        + ws[MSG2 + ((size_t)b * 128 + row) * 128 + 16 * t + n] + msum[t];
                acc[rt][t][reg] = v;
                s += v; ssq += v * v;
            }
            rs[rt][reg] = s; rss[rt][reg] = ssq;
        }
    #pragma unroll
    for (int d = 1; d < 16; d <<= 1) {
        #pragma unroll
        for (int rt = 0; rt < 2; rt++)
            #pragma unroll
            for (int reg = 0; reg < 4; reg++) {
                rs[rt][reg]  += __shfl_xor(rs[rt][reg], d, 64);
                rss[rt][reg] += __shfl_xor(rss[rt][reg], d, 64);
            }
    }
    {
        float s1v[8], o1v[8];
        #pragma unroll
        for (int t = 0; t < 8; t++) { s1v[t] = ln1s[16 * t + n]; o1v[t] = ln1o[16 * t + n]; }
        #pragma unroll
        for (int rt = 0; rt < 2; rt++)
            #pragma unroll
            for (int reg = 0; reg < 4; reg++) {
                float mu = rs[rt][reg] * (1.f / 128);
                float inv = rsqrtf(rss[rt][reg] * (1.f / 128) - mu * mu + EPSF);
                int row = 32 * w + 16 * rt + 4 * q + reg;
                #pragma unroll
                for (int t = 0; t < 8; t++) {
                    float v = fmaxf(s1v[t] * inv * (acc[rt][t][reg] - mu) + o1v[t], 0.f);
                    Ab[row * 136 + 16 * t + n] = f2bf(v);
                }
            }
    }
    __builtin_amdgcn_wave_barrier();   // LN1 writes are wave-local

    // ---- GEMM1 ----
    #pragma unroll
    for (int rt = 0; rt < 2; rt++)
        #pragma unroll
        for (int t = 0; t < 8; t++) acc[rt][t] = 0.f;
    #pragma unroll
    for (int ks = 0; ks < 4; ks++) {
        int k0 = ks * 32 + q * 8;
        short8 a0 = *(const short8*)&Ab[(32 * w + n) * 136 + k0];
        short8 a1 = *(const short8*)&Ab[(32 * w + 16 + n) * 136 + k0];
        #pragma unroll
        for (int t = 0; t < 8; t++) {
            short8 bt = *(const short8*)&prep[W1T_OFF + ((ks * 8 + t) * 64 + lane) * 8];
            acc[0][t] = MFMA16(a0, bt, acc[0][t]);
            acc[1][t] = MFMA16(a1, bt, acc[1][t]);
        }
    }
    // ---- LN2 + relu -> Ab ----
    #pragma unroll
    for (int rt = 0; rt < 2; rt++)
        #pragma unroll
        for (int reg = 0; reg < 4; reg++) {
            float s = 0.f, ssq = 0.f;
            #pragma unroll
            for (int t = 0; t < 8; t++) { float v = acc[rt][t][reg]; s += v; ssq += v * v; }
            rs[rt][reg] = s; rss[rt][reg] = ssq;
        }
    #pragma unroll
    for (int d = 1; d < 16; d <<= 1) {
        #pragma unroll
        for (int rt = 0; rt < 2; rt++)
            #pragma unroll
            for (int reg = 0; reg < 4; reg++) {
                rs[rt][reg]  += __shfl_xor(rs[rt][reg], d, 64);
                rss[rt][reg] += __shfl_xor(rss[rt][reg], d, 64);
            }
    }
    {
        float s2v[8], o2v[8];
        #pragma unroll
        for (int t = 0; t < 8; t++) { s2v[t] = ln2s[16 * t + n]; o2v[t] = ln2o[16 * t + n]; }
        #pragma unroll
        for (int rt = 0; rt < 2; rt++)
            #pragma unroll
            for (int reg = 0; reg < 4; reg++) {
                float mu = rs[rt][reg] * (1.f / 128);
                float inv = rsqrtf(rss[rt][reg] * (1.f / 128) - mu * mu + EPSF);
                int row = 32 * w + 16 * rt + 4 * q + reg;
                #pragma unroll
                for (int t = 0; t < 8; t++) {
                    float v = fmaxf(s2v[t] * inv * (acc[rt][t][reg] - mu) + o2v[t], 0.f);
                    Ab[row * 136 + 16 * t + n] = f2bf(v);
                }
            }
    }
    __builtin_amdgcn_wave_barrier();

    // ---- GEMM2 ----
    #pragma unroll
    for (int rt = 0; rt < 2; rt++)
        #pragma unroll
        for (int t = 0; t < 8; t++) acc[rt][t] = 0.f;
    #pragma unroll
    for (int ks = 0; ks < 4; ks++) {
        int k0 = ks * 32 + q * 8;
        short8 a0 = *(const short8*)&Ab[(32 * w + n) * 136 + k0];
        short8 a1 = *(const short8*)&Ab[(32 * w + 16 + n) * 136 + k0];
        #pragma unroll
        for (int t = 0; t < 8; t++) {
            short8 bt = *(const short8*)&prep[W2T_OFF + ((ks * 8 + t) * 64 + lane) * 8];
            acc[0][t] = MFMA16(a0, bt, acc[0][t]);
            acc[1][t] = MFMA16(a1, bt, acc[1][t]);
        }
    }
    // ---- adj mask + max over rows i ----
    float colmax[8];
    #pragma unroll
    for (int t = 0; t < 8; t++) colmax[t] = NEGF;
    #pragma unroll
    for (int rt = 0; rt < 2; rt++)
        #pragma unroll
        for (int reg = 0; reg < 4; reg++) {
            if (adjm[rt][reg] > 0.f) {
                #pragma unroll
                for (int t = 0; t < 8; t++) colmax[t] = fmaxf(colmax[t], acc[rt][t][reg]);
            }
        }
    #pragma unroll
    for (int t = 0; t < 8; t++) {
        colmax[t] = fmaxf(colmax[t], __shfl_xor(colmax[t], 16, 64));
        colmax[t] = fmaxf(colmax[t], __shfl_xor(colmax[t], 32, 64));
    }
    if (lane < 16) {
        #pragma unroll
        for (int t = 0; t < 8; t++) pw[w * 128 + 16 * t + lane] = colmax[t];
    }
    __syncthreads();   // the one true cross-wave rendezvous
    if (tid < 128) {
        float mx = fmaxf(fmaxf(pw[tid], pw[128 + tid]), fmaxf(pw[256 + tid], pw[384 + tid]));
        out[O_MSG + (size_t)bj * 128 + tid] = mx;
    }
}

// ============================================================
// K3: triplet pooling (blocks 0..255) + final LN (blocks 256..319).
// block 1024.
// ============================================================
constexpr int PSTR = 1032;   // 1032 % 32 = 8
constexpr int QSTR = 1036;   // 1036 % 32 = 12 -> 2-way (free)

__global__ __launch_bounds__(1024) void k_post(
    const float* __restrict__ ws, const void* __restrict__ mask,
    const float* __restrict__ WU3, const float* __restrict__ WU2,
    const float* __restrict__ lnfs, const float* __restrict__ lnfo,
    float* __restrict__ out)
{
    int tid = threadIdx.x;
    __shared__ __align__(16) float smem[16 * PSTR + 16 * QSTR];
    __shared__ unsigned char mloc[128];

    if (blockIdx.x >= 256) {
        // ---------------- final: ret = LN(z@WU1 + msgs@WU2) ----------------
        int blk = blockIdx.x - 256;        // 0..63
        int r8 = tid >> 7, col = tid & 127;
        int bn = blk * 8 + r8;
        float* mrows = smem;               // [8][128]
        float* red   = smem + 1024;        // [32]
        mrows[tid] = out[O_MSG + (size_t)bn * 128 + col];
        __syncthreads();
        float y = ws[ZWU1 + (size_t)bn * 128 + col];
        #pragma unroll 8
        for (int k = 0; k < 128; k++) y += mrows[r8 * 128 + k] * WU2[k * 128 + col];
        float s = y, ss = y * y;
        for (int d = 1; d < 64; d <<= 1) { s += __shfl_xor(s, d, 64); ss += __shfl_xor(ss, d, 64); }
        int wv = tid >> 6;
        if ((tid & 63) == 0) { red[2 * wv] = s; red[2 * wv + 1] = ss; }
        __syncthreads();
        float S = red[4 * r8] + red[4 * r8 + 2], SS = red[4 * r8 + 1] + red[4 * r8 + 3];
        float m_ = S * (1.f / 128), v_ = SS * (1.f / 128) - m_ * m_;
        float r = rsqrtf(v_ + EPSF);
        out[O_RET + (size_t)bn * 128 + col] = lnfs[col] * r * (y - m_) + lnfo[col];
        return;
    }

    // ---------------- triplet max-plus pooling ----------------
    int bx = blockIdx.x;
    int j0 = (bx & 7) * 16, k0 = ((bx >> 3) & 7) * 16, b = bx >> 6;
    int isInt = detect_int(mask);
    float* Pl = smem;               // [16][PSTR]
    float* Ql = smem + 16 * PSTR;   // [16][QSTR]
    float* red    = smem;                  // phase-2 aliases (P region dead)
    float* pooled = smem + 8192;
    float* WU3l   = smem + 8192 + 2048;

    if (tid < 128) mloc[tid] = rdbool(mask, b * 128 + tid, isInt) ? 1 : 0;

    {
        int r     = tid >> 6;        // 0..15 (row)
        int lane63 = tid & 63;
        const float* e1 = ws + E1T + (size_t)(b * 128 + j0 + r) * 1024;
        const float* t1 = ws + TRI1 + (size_t)b * 1024;
        const float* e2 = ws + E2T + (size_t)(b * 128 + k0 + r) * 1024;
        float* pd = Pl + r * PSTR;
        float* qd = Ql + r * QSTR;
        #pragma unroll
        for (int t = 0; t < 4; t++) {
            int off = (t * 64 + lane63) * 4;     // coalesced: 64 lanes x 16B contiguous
            float4 a = *(const float4*)(e1 + off);
            float4 bb = *(const float4*)(t1 + off);
            float4 qv = *(const float4*)(e2 + off);
            pd[off + 0] = a.x + bb.x; pd[off + 1] = a.y + bb.y;
            pd[off + 2] = a.z + bb.z; pd[off + 3] = a.w + bb.w;
            qd[off + 0] = qv.x; qd[off + 1] = qv.y;
            qd[off + 2] = qv.z; qd[off + 3] = qv.w;
        }
    }
    __syncthreads();

    int ic = tid >> 8;
    int tj = (tid >> 4) & 15, tk = tid & 15;
    float accM[8], accU[8];
    #pragma unroll
    for (int c = 0; c < 8; c++) { accM[c] = NEGF; accU[c] = NEGF; }
    {
        const float* pp = Pl + tj * PSTR;
        const float* qq = Ql + tk * QSTR;
        int i1 = ic * 32 + 32;
        for (int ii = ic * 32; ii < i1; ii++) {
            bool m_i = mloc[ii] != 0;
            float4 p0 = *(const float4*)(pp + ii * 8);
            float4 p1 = *(const float4*)(pp + ii * 8 + 4);
            float4 q0 = *(const float4*)(qq + ii * 8);
            float4 q1 = *(const float4*)(qq + ii * 8 + 4);
            float v[8] = { p0.x + q0.x, p0.y + q0.y, p0.z + q0.z, p0.w + q0.w,
                           p1.x + q1.x, p1.y + q1.y, p1.z + q1.z, p1.w + q1.w };
            if (m_i) {
                #pragma unroll
                for (int c = 0; c < 8; c++) accM[c] = fmaxf(accM[c], v[c]);
            } else {
                #pragma unroll
                for (int c = 0; c < 8; c++) accU[c] = fmaxf(accU[c], v[c]);
            }
        }
    }
    float sel[8];
    {
        bool all_i = (mloc[j0 + tj] | mloc[k0 + tk]) != 0;
        #pragma unroll
        for (int c = 0; c < 8; c++) sel[c] = all_i ? fmaxf(accM[c], accU[c]) : accM[c];
    }
    __syncthreads();
    #pragma unroll
    for (int c = 0; c < 8; c++) red[c * 1024 + tid] = sel[c];
    __syncthreads();

    if (tid < 256) {
        int rtj = tid >> 4, rtk = tid & 15;
        const float* t2 = ws + TRI2 + (size_t)(b * 128 + j0 + rtj) * 8;
        const float* t3 = ws + TRI3 + (size_t)(b * 128 + k0 + rtk) * 8;
        const float* e3 = ws + E3N + ((size_t)(b * 128 + j0 + rtj) * 128 + (k0 + rtk)) * 8;
        const float* tg = ws + TRIG + (size_t)b * 8;
        #pragma unroll
        for (int c = 0; c < 8; c++) {
            const float* rc = red + c * 1024 + tid;
            float v = fmaxf(fmaxf(rc[0], rc[256]), fmaxf(rc[512], rc[768]));
            pooled[tid * 8 + c] = v + t2[c] + t3[c] + e3[c] + tg[c];
        }
    } else if (tid < 512) {
        int m = tid - 256;
        *(float4*)(WU3l + m * 4) = *(const float4*)(WU3 + m * 4);
    }
    __syncthreads();

    int col4 = (tid & 31) * 4;
    #pragma unroll
    for (int pass = 0; pass < 8; pass++) {
        int p = pass * 32 + (tid >> 5);
        const float* pl = pooled + p * 8;
        float4 s = { 0.f, 0.f, 0.f, 0.f };
        #pragma unroll
        for (int c = 0; c < 8; c++) {
            float pv = pl[c];
            float4 wv = *(const float4*)(WU3l + c * 128 + col4);
            s.x += pv * wv.x; s.y += pv * wv.y; s.z += pv * wv.z; s.w += pv * wv.w;
        }
        s.x = fmaxf(s.x, 0.f); s.y = fmaxf(s.y, 0.f);
        s.z = fmaxf(s.z, 0.f); s.w = fmaxf(s.w, 0.f);
        int pj = p >> 4, pk = p & 15;
        *(float4*)(out + O_TRI + ((size_t)(b * 128 + j0 + pj) * 128 + (k0 + pk)) * 128 + col4) = s;
    }
}

// ============================================================
extern "C" void kernel_launch(void* const* d_in, const int* in_sizes, int n_in,
                              void* d_out, int out_size, void* d_ws, size_t ws_size,
                              hipStream_t stream)
{
    const float* z    = (const float*)d_in[0];
    const float* e    = (const float*)d_in[1];
    const float* gf   = (const float*)d_in[2];
    const void*  mask = d_in[3];
    const void*  adj  = d_in[4];
    const float* Wt1 = (const float*)d_in[5];
    const float* Wt2 = (const float*)d_in[6];
    const float* Wt3 = (const float*)d_in[7];
    const float* We1 = (const float*)d_in[8];
    const float* We2 = (const float*)d_in[9];
    const float* We3 = (const float*)d_in[10];
    const float* Wg  = (const float*)d_in[11];
    const float* Wm1 = (const float*)d_in[12];
    const float* Wm2 = (const float*)d_in[13];
    const float* Wme = (const float*)d_in[14];
    const float* Wmg = (const float*)d_in[15];
    const float* ln1s = (const float*)d_in[16];
    const float* ln1o = (const float*)d_in[17];
    const float* W1   = (const float*)d_in[18];
    const float* ln2s = (const float*)d_in[19];
    const float* ln2o = (const float*)d_in[20];
    const float* W2   = (const float*)d_in[21];
    const float* WU1  = (const float*)d_in[22];
    const float* WU2  = (const float*)d_in[23];
    const float* WU3  = (const float*)d_in[24];
    const float* lnfs = (const float*)d_in[25];
    const float* lnfo = (const float*)d_in[26];
    float* out = (float*)d_out;
    float* ws  = (float*)d_ws;
    unsigned short* prep = (unsigned short*)(ws + PREPF);

    hipLaunchKernelGGL(k_pre, dim3(724), dim3(256), 0, stream,
                       z, mask, Wt1, Wt2, Wt3, Wm1, Wm2, WU1, gf, Wg, Wmg,
                       W1, W2, Wme, We1, We2, We3, ws, prep);
    hipLaunchKernelGGL(k_main, dim3(1024), dim3(256), 0, stream,
                       e, mask, adj, ln1s, ln1o, ln2s, ln2o, prep, ws, out);
    hipLaunchKernelGGL(k_post, dim3(320), dim3(1024), 0, stream,
                       ws, mask, WU3, WU2, lnfs, lnfo, out);
}

// Round 8
// 209.576 us; speedup vs baseline: 1.2192x; 1.0994x over previous
//
#include <hip/hip_runtime.h>

// Problem constants
#define BN   4
#define NN   128
#define INF  256
#define EF   128
#define OUTF 128
#define EPSF 1e-5f
#define NEGF -998244352.0f   // bf16(1e9); matches the bf16-rounded np reference

typedef __attribute__((ext_vector_type(8))) short short8;
typedef __attribute__((ext_vector_type(4))) float f32x4;

#define MFMA16(a, b, c) __builtin_amdgcn_mfma_f32_16x16x32_bf16(a, b, c, 0, 0, 0)

__device__ __forceinline__ unsigned short f2bf(float f) {
    unsigned u = __float_as_uint(f);
    u += 0x7fffu + ((u >> 16) & 1u);
    return (unsigned short)(u >> 16);
}
__device__ __forceinline__ unsigned pack2(float a, float b) {
    return (unsigned)f2bf(a) | ((unsigned)f2bf(b) << 16);
}

// ---- workspace layout (float offsets) ----
constexpr size_t TRI1 = 0;            // B*N*8   tri_1 (masked)
constexpr size_t TRI2 = 4096;
constexpr size_t TRI3 = 8192;
constexpr size_t MSG1 = 12288;        // B*N*128 msg_1 (masked)
constexpr size_t MSG2 = 77824;
constexpr size_t ZWU1 = 143360;
constexpr size_t TRIG = 208896;       // B*8
constexpr size_t MSGG = 209920;       // B*128
constexpr size_t E1T  = 210944;       // B*N*N*8  [b][j][i][c]
constexpr size_t E2T  = 735232;       // B*N*N*8  [b][k][i][c]
constexpr size_t E3N  = 1259520;      // B*N*N*8  [b][j][k][c]
constexpr size_t PREPF = 1783808;     // bf16 prepped weights (ushort region)

// prep (ushort units), MFMA-fragment order:
// ((ks*8 + t)*64 + lane)*8 + jj == W^T[16t + (lane&15)][ks*32 + (lane>>4)*8 + jj]
constexpr int W1T_OFF  = 0;
constexpr int W2T_OFF  = 16384;
constexpr int WMET_OFF = 32768;

// ---- output layout (float offsets): ret, msgs, tri_msgs ----
constexpr size_t O_RET = 0;
constexpr size_t O_MSG = 65536;
constexpr size_t O_TRI = 131072;

__device__ __forceinline__ int detect_int(const void* mask) {
    const unsigned char* m = (const unsigned char*)mask;
    return (m[1] | m[2] | m[3]) == 0 ? 1 : 0;
}
__device__ __forceinline__ bool rdbool(const void* p, size_t idx, int isInt) {
    if (isInt) return ((const int*)p)[idx] != 0;
    return ((const unsigned char*)p)[idx] != 0;
}

// ============================================================
// K1: tri-e projection (0..511) + z proj (512..1023) + graph (1024..1027)
//     + weight prep (1028..1219).  256 thr.
// tri-e gathers its tiny We weights directly (no prep dependency).
// ============================================================
__global__ __launch_bounds__(256, 4) void k_pre(
    const float* __restrict__ z, const float* __restrict__ e, const void* __restrict__ mask,
    const float* __restrict__ Wt1, const float* __restrict__ Wt2, const float* __restrict__ Wt3,
    const float* __restrict__ Wm1, const float* __restrict__ Wm2, const float* __restrict__ WU1,
    const float* __restrict__ g, const float* __restrict__ Wg, const float* __restrict__ Wmg,
    const float* __restrict__ W1, const float* __restrict__ W2, const float* __restrict__ Wme,
    const float* __restrict__ We1, const float* __restrict__ We2, const float* __restrict__ We3,
    float* __restrict__ ws, unsigned short* __restrict__ prep)
{
    int bx = blockIdx.x, tid = threadIdx.x;
    __shared__ __align__(16) unsigned char smem[128 * 136 * 2];

    if (bx < 512) {
        // ---------- tri-e projection: block = one (b,i) ----------
        unsigned short* Ab = (unsigned short*)smem;
        int bi = bx;
        int b = bi >> 7, i = bi & 127;
        int lane = tid & 63, w = tid >> 6, q = lane >> 4, n = lane & 15;
        // coalesced staging: 2 rows/instr, 32 lanes/row, wave-local rows
        {
            int half = lane >> 5, c4 = (lane & 31) * 4;
            #pragma unroll
            for (int it = 0; it < 16; it++) {
                int row = 32 * w + 2 * it + half;
                float4 v = *(const float4*)(e + (size_t)bi * 16384 + (size_t)row * 128 + c4);
                unsigned* dst = (unsigned*)&Ab[row * 136 + c4];
                dst[0] = pack2(v.x, v.y);
                dst[1] = pack2(v.z, v.w);
            }
        }
        // gather packed-We B fragments (cols: We1|We2|We3|0), L1-hot 4KB arrays
        short8 bfrag[4][2];
        {
            int colbase = n;
            #pragma unroll
            for (int t = 0; t < 2; t++) {
                int col = 16 * t + colbase;
                const float* Wsel = (col < 8) ? We1 : (col < 16 ? We2 : We3);
                int csel = col & 7;
                float mval = (col < 24) ? 1.f : 0.f;
                #pragma unroll
                for (int ks = 0; ks < 4; ks++) {
                    union { short8 s; unsigned short u[8]; } tmp;
                    #pragma unroll
                    for (int jj = 0; jj < 8; jj++) {
                        int k = ks * 32 + q * 8 + jj;
                        tmp.u[jj] = f2bf(Wsel[k * 8 + csel] * mval);
                    }
                    bfrag[ks][t] = tmp.s;
                }
            }
        }
        __builtin_amdgcn_wave_barrier();

        f32x4 ac2[2][2];
        #pragma unroll
        for (int rt = 0; rt < 2; rt++)
            #pragma unroll
            for (int t = 0; t < 2; t++) ac2[rt][t] = 0.f;
        #pragma unroll
        for (int ks = 0; ks < 4; ks++) {
            int k0 = ks * 32 + q * 8;
            short8 a0 = *(const short8*)&Ab[(32 * w + n) * 136 + k0];
            short8 a1 = *(const short8*)&Ab[(32 * w + 16 + n) * 136 + k0];
            #pragma unroll
            for (int t = 0; t < 2; t++) {
                ac2[0][t] = MFMA16(a0, bfrag[ks][t], ac2[0][t]);
                ac2[1][t] = MFMA16(a1, bfrag[ks][t], ac2[1][t]);
            }
        }
        #pragma unroll
        for (int rt = 0; rt < 2; rt++)
            #pragma unroll
            for (int reg = 0; reg < 4; reg++) {
                int row = 32 * w + 16 * rt + 4 * q + reg;
                float v0 = ac2[rt][0][reg];
                if (n < 8) ws[E1T + ((size_t)(b * 128 + row) * 128 + i) * 8 + n] = v0;
                else       ws[E2T + ((size_t)(b * 128 + row) * 128 + i) * 8 + (n - 8)] = v0;
                if (n < 8) ws[E3N + ((size_t)bi * 128 + row) * 8 + n] = ac2[rt][1][reg];
            }
        return;
    }
    if (bx < 1024) {
        // ---------- z-row projections ----------
        int bn = bx - 512;
        int isInt = detect_int(mask);
        float* zr = (float*)smem;
        zr[tid] = z[(size_t)bn * INF + tid];
        __syncthreads();
        float mk = rdbool(mask, bn, isInt) ? 1.f : 0.f;
        for (int idx = tid; idx < 408; idx += 256) {
            const float* W; int c; size_t dst; int width; bool msk;
            if (idx < 8)        { W = Wt1; c = idx;       dst = TRI1 + (size_t)bn * 8;   width = 8;   msk = true;  }
            else if (idx < 16)  { W = Wt2; c = idx - 8;   dst = TRI2 + (size_t)bn * 8;   width = 8;   msk = true;  }
            else if (idx < 24)  { W = Wt3; c = idx - 16;  dst = TRI3 + (size_t)bn * 8;   width = 8;   msk = true;  }
            else if (idx < 152) { W = Wm1; c = idx - 24;  dst = MSG1 + (size_t)bn * 128; width = 128; msk = true;  }
            else if (idx < 280) { W = Wm2; c = idx - 152; dst = MSG2 + (size_t)bn * 128; width = 128; msk = true;  }
            else                { W = WU1; c = idx - 280; dst = ZWU1 + (size_t)bn * 128; width = 128; msk = false; }
            float acc = 0.f;
            #pragma unroll 8
            for (int k = 0; k < INF; k++) acc += zr[k] * W[k * width + c];
            ws[dst + c] = msk ? acc * mk : acc;
        }
        return;
    }
    if (bx < 1028) {
        // ---------- graph_fts projections ----------
        int b = bx - 1024;
        float* gr = (float*)smem;
        if (tid < 128) gr[tid] = g[b * 128 + tid];
        __syncthreads();
        if (tid < 8) {
            float a = 0.f;
            for (int k = 0; k < 128; k++) a += gr[k] * Wg[k * 8 + tid];
            ws[TRIG + b * 8 + tid] = a;
        } else if (tid >= 128) {
            int c = tid - 128;
            float a = 0.f;
            for (int k = 0; k < 128; k++) a += gr[k] * Wmg[k * 128 + c];
            ws[MSGG + b * 128 + c] = a;
        }
        return;
    }
    // ---------- weight prep (fragment-order), W1/W2/Wme only ----------
    {
        int idx = (bx - 1028) * 256 + tid;   // < 49152
        const float* W = (idx < 16384) ? W1 : (idx < 32768 ? W2 : Wme);
        int local = idx & 16383;
        int f = local >> 3, jj = local & 7;
        int lane = f & 63, fg = f >> 6;
        int t = fg & 7, ks = fg >> 3;
        int n = lane & 15, q = lane >> 4;
        int row = 16 * t + n;
        int k = ks * 32 + q * 8 + jj;
        prep[idx] = f2bf(W[k * 128 + row]);
    }
}

// ============================================================
// K2: pair-MLP blocks (bx%3<2, 512 units) + triplet-pool blocks (bx%3==2,
// 256 units).  grid 768, block 256, LDS 36.9KB -> 4 blocks/CU.
// ============================================================
constexpr int PSTR2 = 264;   // floats; conflict-free tj-group reads
constexpr int QSTR2 = 268;   // floats; 268%32=12 -> 2-way (free) tk reads

__global__ __launch_bounds__(256, 4) void k_main(
    const float* __restrict__ e, const void* __restrict__ mask, const void* __restrict__ adj,
    const float* __restrict__ ln1s, const float* __restrict__ ln1o,
    const float* __restrict__ ln2s, const float* __restrict__ ln2o,
    const unsigned short* __restrict__ prep, const float* __restrict__ WU3,
    float* __restrict__ ws, float* __restrict__ out)
{
    int bx = blockIdx.x, tid = threadIdx.x;
    int gct = bx / 3, r3 = bx - gct * 3;
    __shared__ __align__(16) unsigned char smem[128 * 136 * 2 + 2048];
    int lane = tid & 63, w = tid >> 6, q = lane >> 4, n = lane & 15;

    if (r3 == 2) {
        // ================= triplet max-plus pooling: 16x16 (j,k) tile =================
        int g = gct;
        int j0 = ((g >> 3) & 7) * 16, k0 = (g & 7) * 16, b = g >> 6;
        int isInt = detect_int(mask);
        float* Pl = (float*)smem;                       // [16][PSTR2]
        float* Ql = (float*)(smem + 16 * PSTR2 * 4);    // [16][QSTR2]
        float* pooled = Pl;                             // alias after compute
        float* WU3l   = Ql;                             // alias after compute
        __shared__ unsigned char mloc[128];

        if (tid < 128) mloc[tid] = rdbool(mask, b * 128 + tid, isInt) ? 1 : 0;

        int tj = tid >> 4, tk = tid & 15;
        int sr = tid >> 4, seg = tid & 15;   // staging: row sr, 16-float segment seg
        float accM[8], accU[8];
        #pragma unroll
        for (int c = 0; c < 8; c++) { accM[c] = NEGF; accU[c] = NEGF; }

        for (int i0 = 0; i0 < 128; i0 += 32) {
            __syncthreads();
            {
                const float4* e1 = (const float4*)(ws + E1T + (size_t)(b * 128 + j0 + sr) * 1024 + i0 * 8 + seg * 16);
                const float4* t1 = (const float4*)(ws + TRI1 + (size_t)b * 1024 + i0 * 8 + seg * 16);
                const float4* e2 = (const float4*)(ws + E2T + (size_t)(b * 128 + k0 + sr) * 1024 + i0 * 8 + seg * 16);
                float* pd = Pl + sr * PSTR2 + seg * 16;
                float* qd = Ql + sr * QSTR2 + seg * 16;
                #pragma unroll
                for (int t = 0; t < 4; t++) {
                    float4 a = e1[t], bb = t1[t], qv = e2[t];
                    pd[t * 4 + 0] = a.x + bb.x; pd[t * 4 + 1] = a.y + bb.y;
                    pd[t * 4 + 2] = a.z + bb.z; pd[t * 4 + 3] = a.w + bb.w;
                    qd[t * 4 + 0] = qv.x; qd[t * 4 + 1] = qv.y;
                    qd[t * 4 + 2] = qv.z; qd[t * 4 + 3] = qv.w;
                }
            }
            __syncthreads();
            const float* pp = Pl + tj * PSTR2;
            const float* qq = Ql + tk * QSTR2;
            for (int ii = 0; ii < 32; ii++) {
                bool m_i = mloc[i0 + ii] != 0;   // wave-uniform
                float4 p0 = *(const float4*)(pp + ii * 8);
                float4 p1 = *(const float4*)(pp + ii * 8 + 4);
                float4 q0 = *(const float4*)(qq + ii * 8);
                float4 q1 = *(const float4*)(qq + ii * 8 + 4);
                float v[8] = { p0.x + q0.x, p0.y + q0.y, p0.z + q0.z, p0.w + q0.w,
                               p1.x + q1.x, p1.y + q1.y, p1.z + q1.z, p1.w + q1.w };
                if (m_i) {
                    #pragma unroll
                    for (int c = 0; c < 8; c++) accM[c] = fmaxf(accM[c], v[c]);
                } else {
                    #pragma unroll
                    for (int c = 0; c < 8; c++) accU[c] = fmaxf(accU[c], v[c]);
                }
            }
        }
        float sel[8];
        {
            bool all_i = (mloc[j0 + tj] | mloc[k0 + tk]) != 0;
            #pragma unroll
            for (int c = 0; c < 8; c++) sel[c] = all_i ? fmaxf(accM[c], accU[c]) : accM[c];
        }
        __syncthreads();   // P/Q reads done; safe to alias
        {
            const float* t2 = ws + TRI2 + (size_t)(b * 128 + j0 + tj) * 8;
            const float* t3 = ws + TRI3 + (size_t)(b * 128 + k0 + tk) * 8;
            const float* e3 = ws + E3N + ((size_t)(b * 128 + j0 + tj) * 128 + (k0 + tk)) * 8;
            const float* tg = ws + TRIG + (size_t)b * 8;
            #pragma unroll
            for (int c = 0; c < 8; c++)
                pooled[tid * 8 + c] = sel[c] + t2[c] + t3[c] + e3[c] + tg[c];
            *(float4*)(WU3l + tid * 4) = *(const float4*)(WU3 + tid * 4);
        }
        __syncthreads();
        // epilogue: relu(pooled @ WU3), float4 coalesced stores
        int col4 = (tid & 31) * 4, rowgrp = tid >> 5;
        #pragma unroll
        for (int pass = 0; pass < 32; pass++) {
            int p = pass * 8 + rowgrp;
            const float* pl = pooled + p * 8;
            float4 s = { 0.f, 0.f, 0.f, 0.f };
            #pragma unroll
            for (int c = 0; c < 8; c++) {
                float pv = pl[c];
                float4 wv = *(const float4*)(WU3l + c * 128 + col4);
                s.x += pv * wv.x; s.y += pv * wv.y; s.z += pv * wv.z; s.w += pv * wv.w;
            }
            s.x = fmaxf(s.x, 0.f); s.y = fmaxf(s.y, 0.f);
            s.z = fmaxf(s.z, 0.f); s.w = fmaxf(s.w, 0.f);
            int pj = p >> 4, pk = p & 15;
            *(float4*)(out + O_TRI + ((size_t)(b * 128 + j0 + pj) * 128 + (k0 + pk)) * 128 + col4) = s;
        }
        return;
    }

    // ================= pair MLP: block = one (b,j) =================
    unsigned short* Ab = (unsigned short*)smem;
    float* pw = (float*)(smem + 128 * 136 * 2);
    int bj = gct * 2 + r3;
    int b = bj >> 7, j = bj & 127;
    int isInt = detect_int(mask);

    {
        int half = lane >> 5, c4 = (lane & 31) * 4;
        #pragma unroll
        for (int it = 0; it < 16; it++) {
            int row = 32 * w + 2 * it + half;
            float4 v = *(const float4*)(e + (((size_t)b * 128 + row) * 128 + j) * 128 + c4);
            unsigned* dst = (unsigned*)&Ab[row * 136 + c4];
            dst[0] = pack2(v.x, v.y);
            dst[1] = pack2(v.z, v.w);
        }
    }
    __builtin_amdgcn_wave_barrier();

    f32x4 acc[2][8];
    #pragma unroll
    for (int rt = 0; rt < 2; rt++)
        #pragma unroll
        for (int t = 0; t < 8; t++) acc[rt][t] = 0.f;

    #pragma unroll
    for (int ks = 0; ks < 4; ks++) {
        int k0 = ks * 32 + q * 8;
        short8 a0 = *(const short8*)&Ab[(32 * w + n) * 136 + k0];
        short8 a1 = *(const short8*)&Ab[(32 * w + 16 + n) * 136 + k0];
        #pragma unroll
        for (int t = 0; t < 8; t++) {
            short8 bt = *(const short8*)&prep[WMET_OFF + ((ks * 8 + t) * 64 + lane) * 8];
            acc[0][t] = MFMA16(a0, bt, acc[0][t]);
            acc[1][t] = MFMA16(a1, bt, acc[1][t]);
        }
    }

    float msum[8];
    #pragma unroll
    for (int t = 0; t < 8; t++)
        msum[t] = ws[MSG1 + (size_t)bj * 128 + 16 * t + n] + ws[MSGG + (size_t)b * 128 + 16 * t + n];
    float adjm[2][4];
    float rs[2][4], rss[2][4];
    #pragma unroll
    for (int rt = 0; rt < 2; rt++)
        #pragma unroll
        for (int reg = 0; reg < 4; reg++) {
            int row = 32 * w + 16 * rt + 4 * q + reg;
            bool av = rdbool(adj, ((size_t)b * 128 + row) * 128 + j, isInt);
            adjm[rt][reg] = av ? 1.f : 0.f;
            float s = 0.f, ssq = 0.f;
            #pragma unroll
            for (int t = 0; t < 8; t++) {
                float v = acc[rt][t][reg] * adjm[rt][reg]
                        + ws[MSG2 + ((size_t)b * 128 + row) * 128 + 16 * t + n] + msum[t];
                acc[rt][t][reg] = v;
                s += v; ssq += v * v;
            }
            rs[rt][reg] = s; rss[rt][reg] = ssq;
        }
    #pragma unroll
    for (int d = 1; d < 16; d <<= 1) {
        #pragma unroll
        for (int rt = 0; rt < 2; rt++)
            #pragma unroll
            for (int reg = 0; reg < 4; reg++) {
                rs[rt][reg]  += __shfl_xor(rs[rt][reg], d, 64);
                rss[rt][reg] += __shfl_xor(rss[rt][reg], d, 64);
            }
    }
    {
        float s1v[8], o1v[8];
        #pragma unroll
        for (int t = 0; t < 8; t++) { s1v[t] = ln1s[16 * t + n]; o1v[t] = ln1o[16 * t + n]; }
        #pragma unroll
        for (int rt = 0; rt < 2; rt++)
            #pragma unroll
            for (int reg = 0; reg < 4; reg++) {
                float mu = rs[rt][reg] * (1.f / 128);
                float inv = rsqrtf(rss[rt][reg] * (1.f / 128) - mu * mu + EPSF);
                int row = 32 * w + 16 * rt + 4 * q + reg;
                #pragma unroll
                for (int t = 0; t < 8; t++) {
                    float v = fmaxf(s1v[t] * inv * (acc[rt][t][reg] - mu) + o1v[t], 0.f);
                    Ab[row * 136 + 16 * t + n] = f2bf(v);
                }
            }
    }
    __builtin_amdgcn_wave_barrier();

    #pragma unroll
    for (int rt = 0; rt < 2; rt++)
        #pragma unroll
        for (int t = 0; t < 8; t++) acc[rt][t] = 0.f;
    #pragma unroll
    for (int ks = 0; ks < 4; ks++) {
        int k0 = ks * 32 + q * 8;
        short8 a0 = *(const short8*)&Ab[(32 * w + n) * 136 + k0];
        short8 a1 = *(const short8*)&Ab[(32 * w + 16 + n) * 136 + k0];
        #pragma unroll
        for (int t = 0; t < 8; t++) {
            short8 bt = *(const short8*)&prep[W1T_OFF + ((ks * 8 + t) * 64 + lane) * 8];
            acc[0][t] = MFMA16(a0, bt, acc[0][t]);
            acc[1][t] = MFMA16(a1, bt, acc[1][t]);
        }
    }
    #pragma unroll
    for (int rt = 0; rt < 2; rt++)
        #pragma unroll
        for (int reg = 0; reg < 4; reg++) {
            float s = 0.f, ssq = 0.f;
            #pragma unroll
            for (int t = 0; t < 8; t++) { float v = acc[rt][t][reg]; s += v; ssq += v * v; }
            rs[rt][reg] = s; rss[rt][reg] = ssq;
        }
    #pragma unroll
    for (int d = 1; d < 16; d <<= 1) {
        #pragma unroll
        for (int rt = 0; rt < 2; rt++)
            #pragma unroll
            for (int reg = 0; reg < 4; reg++) {
                rs[rt][reg]  += __shfl_xor(rs[rt][reg], d, 64);
                rss[rt][reg] += __shfl_xor(rss[rt][reg], d, 64);
            }
    }
    {
        float s2v[8], o2v[8];
        #pragma unroll
        for (int t = 0; t < 8; t++) { s2v[t] = ln2s[16 * t + n]; o2v[t] = ln2o[16 * t + n]; }
        #pragma unroll
        for (int rt = 0; rt < 2; rt++)
            #pragma unroll
            for (int reg = 0; reg < 4; reg++) {
                float mu = rs[rt][reg] * (1.f / 128);
                float inv = rsqrtf(rss[rt][reg] * (1.f / 128) - mu * mu + EPSF);
                int row = 32 * w + 16 * rt + 4 * q + reg;
                #pragma unroll
                for (int t = 0; t < 8; t++) {
                    float v = fmaxf(s2v[t] * inv * (acc[rt][t][reg] - mu) + o2v[t], 0.f);
                    Ab[row * 136 + 16 * t + n] = f2bf(v);
                }
            }
    }
    __builtin_amdgcn_wave_barrier();

    #pragma unroll
    for (int rt = 0; rt < 2; rt++)
        #pragma unroll
        for (int t = 0; t < 8; t++) acc[rt][t] = 0.f;
    #pragma unroll
    for (int ks = 0; ks < 4; ks++) {
        int k0 = ks * 32 + q * 8;
        short8 a0 = *(const short8*)&Ab[(32 * w + n) * 136 + k0];
        short8 a1 = *(const short8*)&Ab[(32 * w + 16 + n) * 136 + k0];
        #pragma unroll
        for (int t = 0; t < 8; t++) {
            short8 bt = *(const short8*)&prep[W2T_OFF + ((ks * 8 + t) * 64 + lane) * 8];
            acc[0][t] = MFMA16(a0, bt, acc[0][t]);
            acc[1][t] = MFMA16(a1, bt, acc[1][t]);
        }
    }
    float colmax[8];
    #pragma unroll
    for (int t = 0; t < 8; t++) colmax[t] = NEGF;
    #pragma unroll
    for (int rt = 0; rt < 2; rt++)
        #pragma unroll
        for (int reg = 0; reg < 4; reg++) {
            if (adjm[rt][reg] > 0.f) {
                #pragma unroll
                for (int t = 0; t < 8; t++) colmax[t] = fmaxf(colmax[t], acc[rt][t][reg]);
            }
        }
    #pragma unroll
    for (int t = 0; t < 8; t++) {
        colmax[t] = fmaxf(colmax[t], __shfl_xor(colmax[t], 16, 64));
        colmax[t] = fmaxf(colmax[t], __shfl_xor(colmax[t], 32, 64));
    }
    if (lane < 16) {
        #pragma unroll
        for (int t = 0; t < 8; t++) pw[w * 128 + 16 * t + lane] = colmax[t];
    }
    __syncthreads();
    if (tid < 128) {
        float mx = fmaxf(fmaxf(pw[tid], pw[128 + tid]), fmaxf(pw[256 + tid], pw[384 + tid]));
        out[O_MSG + (size_t)bj * 128 + tid] = mx;
    }
}

// ============================================================
// K3: ret = LN(z@WU1 + msgs@WU2).  grid 512, block 128
// ============================================================
__global__ __launch_bounds__(128) void k_final(
    const float* __restrict__ ws, const float* __restrict__ WU2,
    const float* __restrict__ lnfs, const float* __restrict__ lnfo,
    float* __restrict__ out)
{
    int bn = blockIdx.x, tid = threadIdx.x;
    __shared__ float mrow[128];
    __shared__ float red[4];
    mrow[tid] = out[O_MSG + (size_t)bn * 128 + tid];
    __syncthreads();
    float y = ws[ZWU1 + (size_t)bn * 128 + tid];
    #pragma unroll 8
    for (int k = 0; k < 128; k++) y += mrow[k] * WU2[k * 128 + tid];
    float s = y, ss = y * y;
    for (int d = 1; d < 64; d <<= 1) { s += __shfl_xor(s, d, 64); ss += __shfl_xor(ss, d, 64); }
    if ((tid & 63) == 0) { red[(tid >> 6) * 2] = s; red[(tid >> 6) * 2 + 1] = ss; }
    __syncthreads();
    float S = red[0] + red[2], SS = red[1] + red[3];
    float m_ = S * (1.f / 128), v_ = SS * (1.f / 128) - m_ * m_;
    float r = rsqrtf(v_ + EPSF);
    out[O_RET + (size_t)bn * 128 + tid] = lnfs[tid] * r * (y - m_) + lnfo[tid];
}

// ============================================================
extern "C" void kernel_launch(void* const* d_in, const int* in_sizes, int n_in,
                              void* d_out, int out_size, void* d_ws, size_t ws_size,
                              hipStream_t stream)
{
    const float* z    = (const float*)d_in[0];
    const float* e    = (const float*)d_in[1];
    const float* gf   = (const float*)d_in[2];
    const void*  mask = d_in[3];
    const void*  adj  = d_in[4];
    const float* Wt1 = (const float*)d_in[5];
    const float* Wt2 = (const float*)d_in[6];
    const float* Wt3 = (const float*)d_in[7];
    const float* We1 = (const float*)d_in[8];
    const float* We2 = (const float*)d_in[9];
    const float* We3 = (const float*)d_in[10];
    const float* Wg  = (const float*)d_in[11];
    const float* Wm1 = (const float*)d_in[12];
    const float* Wm2 = (const float*)d_in[13];
    const float* Wme = (const float*)d_in[14];
    const float* Wmg = (const float*)d_in[15];
    const float* ln1s = (const float*)d_in[16];
    const float* ln1o = (const float*)d_in[17];
    const float* W1   = (const float*)d_in[18];
    const float* ln2s = (const float*)d_in[19];
    const float* ln2o = (const float*)d_in[20];
    const float* W2   = (const float*)d_in[21];
    const float* WU1  = (const float*)d_in[22];
    const float* WU2  = (const float*)d_in[23];
    const float* WU3  = (const float*)d_in[24];
    const float* lnfs = (const float*)d_in[25];
    const float* lnfo = (const float*)d_in[26];
    float* out = (float*)d_out;
    float* ws  = (float*)d_ws;
    unsigned short* prep = (unsigned short*)(ws + PREPF);

    hipLaunchKernelGGL(k_pre, dim3(1220), dim3(256), 0, stream,
                       z, e, mask, Wt1, Wt2, Wt3, Wm1, Wm2, WU1, gf, Wg, Wmg,
                       W1, W2, Wme, We1, We2, We3, ws, prep);
    hipLaunchKernelGGL(k_main, dim3(768), dim3(256), 0, stream,
                       e, mask, adj, ln1s, ln1o, ln2s, ln2o, prep, WU3, ws, out);
    hipLaunchKernelGGL(k_final, dim3(512), dim3(128), 0, stream,
                       ws, WU2, lnfs, lnfo, out);
}